// Round 9
// baseline (414.641 us; speedup 1.0000x reference)
//
#include <hip/hip_runtime.h>
#include <math.h>

#define NN 100000       // N_NODES
#define NE 800000       // N_EDGES
#define DN 64           // D_NODE
#define DE 4            // D_EDGE
#define HH 128          // H_MSG == H_UPD
#define NT 64           // nodes per block (k_xproj)
#define NT2 64          // nodes per block (k_update, MFMA)
#define SCAN_B 256
#define NBLK_SCAN ((NN + SCAN_B - 1) / SCAN_B)   // 391

using bf16x8 = __attribute__((ext_vector_type(8))) short;
using f32x4  = __attribute__((ext_vector_type(4))) float;

// bf16 helpers (manual, RNE)
__device__ __forceinline__ unsigned short f2bf(float f) {
    unsigned int u = __float_as_uint(f);
    unsigned int r = (u + 0x7fffu + ((u >> 16) & 1u)) >> 16;
    return (unsigned short)r;
}
__device__ __forceinline__ float bf2f(unsigned short h) {
    return __uint_as_float(((unsigned int)h) << 16);
}
__device__ __forceinline__ float2 bfpair2f(unsigned int v) {
    return make_float2(__uint_as_float(v << 16),
                       __uint_as_float(v & 0xffff0000u));
}

// ---------------------------------------------------------------------------
// Kernel 1: XA(bf16) = x @ W1[0:64,:], XB(f32) = x @ W1[64:128,:]
// ---------------------------------------------------------------------------
__global__ __launch_bounds__(256) void k_xproj(const float* __restrict__ x,
                                               const float* __restrict__ W1,
                                               unsigned short* __restrict__ XAb,
                                               float* __restrict__ XB) {
    __shared__ float xsT[DN][NT];
    const int n0 = blockIdx.x * NT;
    const int t  = threadIdx.x;
    {
        const int i  = t & 63;
        const int k0 = (t >> 6) * 16;
        const int n  = n0 + i;
        if (n < NN) {
            const float4* src = (const float4*)(x + (size_t)n * DN + k0);
#pragma unroll
            for (int q = 0; q < 4; ++q) {
                float4 v = src[q];
                xsT[k0 + q * 4 + 0][i] = v.x;
                xsT[k0 + q * 4 + 1][i] = v.y;
                xsT[k0 + q * 4 + 2][i] = v.z;
                xsT[k0 + q * 4 + 3][i] = v.w;
            }
        } else {
#pragma unroll
            for (int q = 0; q < 16; ++q) xsT[k0 + q][i] = 0.f;
        }
    }
    __syncthreads();

    const int cg = t & 31;
    const int ng = t >> 5;
    const int c0 = cg * 8;
    const float* wbase = (c0 < HH) ? (W1 + c0) : (W1 + (size_t)DN * HH + (c0 - HH));

    float acc[8][8];
#pragma unroll
    for (int i = 0; i < 8; ++i)
#pragma unroll
        for (int c = 0; c < 8; ++c) acc[i][c] = 0.f;

#pragma unroll 2
    for (int k = 0; k < DN; ++k) {
        float4 xa = *(const float4*)&xsT[k][ng * 8];
        float4 xb = *(const float4*)&xsT[k][ng * 8 + 4];
        float4 w0 = *(const float4*)(wbase + (size_t)k * HH);
        float4 w1 = *(const float4*)(wbase + (size_t)k * HH + 4);
        const float xi[8] = {xa.x, xa.y, xa.z, xa.w, xb.x, xb.y, xb.z, xb.w};
        const float wc[8] = {w0.x, w0.y, w0.z, w0.w, w1.x, w1.y, w1.z, w1.w};
#pragma unroll
        for (int i = 0; i < 8; ++i)
#pragma unroll
            for (int c = 0; c < 8; ++c) acc[i][c] = fmaf(xi[i], wc[c], acc[i][c]);
    }

    if (c0 < HH) {
#pragma unroll
        for (int i = 0; i < 8; ++i) {
            const int n = n0 + ng * 8 + i;
            if (n < NN) {
                unsigned short tmp[8];
#pragma unroll
                for (int c = 0; c < 8; ++c) tmp[c] = f2bf(acc[i][c]);
                *(uint4*)(XAb + (size_t)n * HH + c0) = *(const uint4*)tmp;
            }
        }
    } else {
#pragma unroll
        for (int i = 0; i < 8; ++i) {
            const int n = n0 + ng * 8 + i;
            if (n < NN) {
                float* dst = XB + (size_t)n * HH + (c0 - HH);
                *(float4*)(dst)     = make_float4(acc[i][0], acc[i][1], acc[i][2], acc[i][3]);
                *(float4*)(dst + 4) = make_float4(acc[i][4], acc[i][5], acc[i][6], acc[i][7]);
            }
        }
    }
}

// ---------------------------------------------------------------------------
// Fold kernel: Wc = W2 @ U1[64:128,:];  cvec = b2 @ U1[64:128,:]
// ---------------------------------------------------------------------------
__global__ __launch_bounds__(256) void k_fold(const float* __restrict__ W2,
                                              const float* __restrict__ U1,
                                              const float* __restrict__ b2,
                                              float* __restrict__ Wc,
                                              float* __restrict__ cvec) {
    const int idx = blockIdx.x * 256 + threadIdx.x;
    const float* u1b = U1 + (size_t)DN * HH;
    if (blockIdx.x < 64) {
        const int r = idx >> 7;
        const int c = idx & 127;
        float acc = 0.f;
#pragma unroll 8
        for (int j = 0; j < DN; ++j)
            acc = fmaf(W2[(size_t)r * DN + j], u1b[(size_t)j * HH + c], acc);
        Wc[(size_t)r * HH + c] = acc;
    } else if (threadIdx.x < HH) {
        const int c = threadIdx.x;
        float acc = 0.f;
#pragma unroll 8
        for (int j = 0; j < DN; ++j)
            acc = fmaf(b2[j], u1b[(size_t)j * HH + c], acc);
        cvec[c] = acc;
    }
}

// ---------------------------------------------------------------------------
// Pack kernel: weights -> bf16 B-fragment layout for mfma_f32_16x16x32_bf16.
// ---------------------------------------------------------------------------
__global__ __launch_bounds__(256) void k_pack(const float* __restrict__ U1,
                                              const float* __restrict__ Wc,
                                              const float* __restrict__ U2,
                                              unsigned short* __restrict__ Wpa,
                                              unsigned short* __restrict__ Wpb) {
    const int tid = blockIdx.x * 256 + threadIdx.x;
    if (tid < 3072) {
        const int l  = tid & 63;
        const int kb = (tid >> 6) % 6;
        const int n  = tid / 384;
        const int kbase = kb * 32 + (l >> 4) * 8;
        const int col   = n * 16 + (l & 15);
        unsigned short tmp[8];
#pragma unroll
        for (int j = 0; j < 8; ++j) {
            const int k = kbase + j;
            const float v = (k < DN) ? U1[(size_t)k * HH + col]
                                     : Wc[(size_t)(k - DN) * HH + col];
            tmp[j] = f2bf(v);
        }
        *(uint4*)(Wpa + (size_t)tid * 8) = *(const uint4*)tmp;
    } else if (tid < 4096) {
        const int t2 = tid - 3072;
        const int l  = t2 & 63;
        const int kb = (t2 >> 6) & 3;
        const int n2 = t2 >> 8;
        const int kbase = kb * 32 + (l >> 4) * 8;
        const int col   = n2 * 16 + (l & 15);
        unsigned short tmp[8];
#pragma unroll
        for (int j = 0; j < 8; ++j) tmp[j] = f2bf(U2[(size_t)(kbase + j) * DN + col]);
        *(uint4*)(Wpb + (size_t)t2 * 8) = *(const uint4*)tmp;
    }
}

// ---------------------------------------------------------------------------
// Counting sort by destination
// ---------------------------------------------------------------------------
__global__ __launch_bounds__(256) void k_hist(const int* __restrict__ ei,
                                              int* __restrict__ cnt) {
    const int e = blockIdx.x * 256 + threadIdx.x;
    if (e < NE) atomicAdd(&cnt[ei[NE + e]], 1);
}

__global__ __launch_bounds__(SCAN_B) void k_scan_a(const int* __restrict__ cnt,
                                                   int* __restrict__ pos,
                                                   int* __restrict__ bsum) {
    __shared__ int sh[SCAN_B];
    const int n = blockIdx.x * SCAN_B + threadIdx.x;
    const int c = (n < NN) ? cnt[n] : 0;
    sh[threadIdx.x] = c;
    __syncthreads();
    int v = c;
#pragma unroll
    for (int off = 1; off < SCAN_B; off <<= 1) {
        int add = (threadIdx.x >= off) ? sh[threadIdx.x - off] : 0;
        __syncthreads();
        v += add;
        sh[threadIdx.x] = v;
        __syncthreads();
    }
    if (n < NN) pos[n] = v - c;
    if (threadIdx.x == SCAN_B - 1) bsum[blockIdx.x] = v;
}

__global__ __launch_bounds__(512) void k_scan_b(int* __restrict__ bsum) {
    __shared__ int sh[512];
    const int i = threadIdx.x;
    const int c = (i < NBLK_SCAN) ? bsum[i] : 0;
    sh[i] = c;
    __syncthreads();
    int v = c;
#pragma unroll
    for (int off = 1; off < 512; off <<= 1) {
        int add = (i >= off) ? sh[i - off] : 0;
        __syncthreads();
        v += add;
        sh[i] = v;
        __syncthreads();
    }
    if (i < NBLK_SCAN) bsum[i] = v - c;
}

__global__ __launch_bounds__(256) void k_scatter(const int* __restrict__ ei,
                                                 const float* __restrict__ ef,
                                                 int* __restrict__ pos,
                                                 const int* __restrict__ boff,
                                                 int* __restrict__ es,
                                                 float4* __restrict__ ef4) {
    const int e = blockIdx.x * 256 + threadIdx.x;
    if (e >= NE) return;
    const int s = ei[e];
    const int d = ei[NE + e];
    const int slot = atomicAdd(&pos[d], 1) + boff[d >> 8];
    es[slot] = s;
    ef4[slot] = make_float4(log1pf(ef[e * 4 + 0]), log1pf(ef[e * 4 + 1]),
                            log1pf(ef[e * 4 + 2]), log1pf(ef[e * 4 + 3]));
}

// ---------------------------------------------------------------------------
// Segmented reduce, one wave per node. 8-deep register pipeline on the
// es->XAb gather chain: 8 edges in flight per wave, static slot indices.
// ---------------------------------------------------------------------------
#define AGG_STEP(AV, FV)                                              \
    {                                                                 \
        const float2 a_ = bfpair2f(AV);                               \
        const float4 f_ = FV;                                         \
        float h0 = a_.x + base0;                                      \
        float h1 = a_.y + base1;                                      \
        h0 = fmaf(f_.x, wv0.x, h0); h0 = fmaf(f_.y, wv1.x, h0);       \
        h0 = fmaf(f_.z, wv2.x, h0); h0 = fmaf(f_.w, wv3.x, h0);       \
        h1 = fmaf(f_.x, wv0.y, h1); h1 = fmaf(f_.y, wv1.y, h1);       \
        h1 = fmaf(f_.z, wv2.y, h1); h1 = fmaf(f_.w, wv3.y, h1);       \
        acc0 += fmaxf(h0, 0.f);                                       \
        acc1 += fmaxf(h1, 0.f);                                       \
    }

__global__ __launch_bounds__(256) void k_agg(const int* __restrict__ es,
                                             const float4* __restrict__ ef4,
                                             const int* __restrict__ pos,
                                             const int* __restrict__ boff,
                                             const int* __restrict__ cnt,
                                             const unsigned short* __restrict__ XAb,
                                             const float* __restrict__ XB,
                                             const float* __restrict__ W1,
                                             const float* __restrict__ b1,
                                             float* __restrict__ Hagg,
                                             float* __restrict__ deg) {
    const int wave = threadIdx.x >> 6;
    const int lane = threadIdx.x & 63;
    const int d = blockIdx.x * 4 + wave;
    if (d >= NN) return;
    const int c     = cnt[d];
    const int end   = pos[d] + boff[d >> 8];
    const int start = end - c;
    const int j0    = lane * 2;

    const float* we = W1 + 128 * HH;
    const float2 xb = *(const float2*)(XB + (size_t)d * HH + j0);
    const float2 bb = *(const float2*)(b1 + j0);
    const float base0 = xb.x + bb.x;
    const float base1 = xb.y + bb.y;
    const float2 wv0 = *(const float2*)(we + 0 * HH + j0);
    const float2 wv1 = *(const float2*)(we + 1 * HH + j0);
    const float2 wv2 = *(const float2*)(we + 2 * HH + j0);
    const float2 wv3 = *(const float2*)(we + 3 * HH + j0);

    float acc0 = 0.f, acc1 = 0.f;

    unsigned int av[8];
    float4 fv[8];
#pragma unroll
    for (int s = 0; s < 8; ++s) {
        if (start + s < end) {
            av[s] = *(const unsigned int*)(XAb + (size_t)es[start + s] * HH + j0);
            fv[s] = ef4[start + s];
        }
    }
    int k = start;
    for (; k + 16 <= end; k += 8) {
#pragma unroll
        for (int s = 0; s < 8; ++s) {
            const unsigned int a_now = av[s];
            const float4 f_now = fv[s];
            // reload slot for edge k+8+s (guaranteed < end by loop condition)
            av[s] = *(const unsigned int*)(XAb + (size_t)es[k + 8 + s] * HH + j0);
            fv[s] = ef4[k + 8 + s];
            AGG_STEP(a_now, f_now);
        }
    }
    // drain loaded slots (edges k .. min(end, k+8)-1)
    {
        const int rem = end - k;   // 0..15
#pragma unroll
        for (int s = 0; s < 8; ++s) {
            if (s < rem) AGG_STEP(av[s], fv[s]);
        }
    }
    // scalar tail for edges k+8 .. end-1 (only when rem > 8)
    for (int kk = k + 8; kk < end; ++kk) {
        const unsigned int a = *(const unsigned int*)(XAb + (size_t)es[kk] * HH + j0);
        const float4 f = ef4[kk];
        AGG_STEP(a, f);
    }

    *(float2*)(Hagg + (size_t)d * HH + j0) = make_float2(acc0, acc1);
    if (lane == 0) deg[d] = (float)c;
}

// ---------------------------------------------------------------------------
// Fallback edge kernel (atomic path)
// ---------------------------------------------------------------------------
__global__ __launch_bounds__(256) void k_edge_atomic(const int* __restrict__ ei,
                                                     const float* __restrict__ ef,
                                                     const float* __restrict__ W1,
                                                     const float* __restrict__ b1,
                                                     const unsigned short* __restrict__ XAb,
                                                     const float* __restrict__ XB,
                                                     float* __restrict__ Hagg,
                                                     float* __restrict__ deg) {
    const int wave = threadIdx.x >> 6;
    const int lane = threadIdx.x & 63;
    const long e = (long)blockIdx.x * 4 + wave;
    if (e >= NE) return;
    const int s = ei[e];
    const int d = ei[NE + e];

    float t = 0.f;
    if (lane < DE) t = log1pf(ef[e * DE + lane]);
    const float l0 = __shfl(t, 0);
    const float l1 = __shfl(t, 1);
    const float l2 = __shfl(t, 2);
    const float l3 = __shfl(t, 3);

    const float* we = W1 + 128 * HH;
    const size_t sb = (size_t)s * HH;
    const size_t db = (size_t)d * HH;
#pragma unroll
    for (int r = 0; r < 2; ++r) {
        const int j = lane + r * 64;
        float h = bf2f(XAb[sb + j]) + XB[db + j] + b1[j];
        h = fmaf(l0, we[0 * HH + j], h);
        h = fmaf(l1, we[1 * HH + j], h);
        h = fmaf(l2, we[2 * HH + j], h);
        h = fmaf(l3, we[3 * HH + j], h);
        h = fmaxf(h, 0.f);
        atomicAdd(&Hagg[db + j], h);
    }
    if (lane == 0) atomicAdd(&deg[d], 1.f);
}

// ---------------------------------------------------------------------------
// Kernel 3 (MFMA): 64 nodes/block, 4 waves, one 16-row m-tile per wave.
// ---------------------------------------------------------------------------
__global__ __launch_bounds__(256) void k_update(const float* __restrict__ x,
                                                const float* __restrict__ Hagg,
                                                const float* __restrict__ deg,
                                                const unsigned short* __restrict__ Wpa,
                                                const unsigned short* __restrict__ Wpb,
                                                const float* __restrict__ cvec,
                                                const float* __restrict__ bu1,
                                                const float* __restrict__ bu2,
                                                float* __restrict__ out) {
    __shared__ unsigned short sA[6 * 4 * 64 * 8];   // 24 KB
    __shared__ float sdeg[NT2];
    const int n0 = blockIdx.x * NT2;
    const int t  = threadIdx.x;
    const int w    = t >> 6;
    const int l    = t & 63;
    const int quad = l >> 4;
    const int l16  = l & 15;

#pragma unroll
    for (int it = 0; it < 4; ++it) {
        const int flat = t + it * 256;
        const int node = flat >> 4;
        const int c    = flat & 15;
        const int gn   = n0 + node;
        float4 v = make_float4(0.f, 0.f, 0.f, 0.f);
        if (gn < NN) v = *(const float4*)(x + (size_t)gn * DN + c * 4);
        const int k = c * 4, Q = k >> 3, j0 = k & 7;
        uint2 pk;
        pk.x = (unsigned)f2bf(v.x) | ((unsigned)f2bf(v.y) << 16);
        pk.y = (unsigned)f2bf(v.z) | ((unsigned)f2bf(v.w) << 16);
        *(uint2*)(&sA[(Q * 64 + node) * 8 + j0]) = pk;
    }
#pragma unroll
    for (int it = 0; it < 8; ++it) {
        const int flat = t + it * 256;
        const int node = flat >> 5;
        const int c    = flat & 31;
        const int gn   = n0 + node;
        float4 v = make_float4(0.f, 0.f, 0.f, 0.f);
        if (gn < NN) v = *(const float4*)(Hagg + (size_t)gn * HH + c * 4);
        const int k = DN + c * 4, Q = k >> 3, j0 = k & 7;
        uint2 pk;
        pk.x = (unsigned)f2bf(v.x) | ((unsigned)f2bf(v.y) << 16);
        pk.y = (unsigned)f2bf(v.z) | ((unsigned)f2bf(v.w) << 16);
        *(uint2*)(&sA[(Q * 64 + node) * 8 + j0]) = pk;
    }
    if (t < NT2) sdeg[t] = (n0 + t < NN) ? deg[n0 + t] : 0.f;
    __syncthreads();

    f32x4 acc[8];
#pragma unroll
    for (int n = 0; n < 8; ++n) {
        const int col = n * 16 + l16;
        const float bv = bu1[col];
        const float cv = cvec[col];
#pragma unroll
        for (int r = 0; r < 4; ++r)
            acc[n][r] = fmaf(sdeg[w * 16 + quad * 4 + r], cv, bv);
    }
    const int mrow = w * 16 + l16;
#pragma unroll
    for (int kb = 0; kb < 6; ++kb) {
        bf16x8 a = *(const bf16x8*)(const void*)(&sA[((kb * 4 + quad) * 64 + mrow) * 8]);
#pragma unroll
        for (int n = 0; n < 8; ++n) {
            bf16x8 b = *(const bf16x8*)(const void*)(Wpa + ((size_t)(n * 6 + kb) * 64 + l) * 8);
            acc[n] = __builtin_amdgcn_mfma_f32_16x16x32_bf16(a, b, acc[n], 0, 0, 0);
        }
    }
    __syncthreads();

#pragma unroll
    for (int n = 0; n < 8; ++n) {
        const int col = n * 16 + l16;
        const int Q = col >> 3;
        const int j = col & 7;
#pragma unroll
        for (int r = 0; r < 4; ++r) {
            const int m = w * 16 + quad * 4 + r;
            sA[(Q * 64 + m) * 8 + j] = f2bf(fmaxf(acc[n][r], 0.f));
        }
    }
    __syncthreads();

    f32x4 acc2[4];
#pragma unroll
    for (int n2 = 0; n2 < 4; ++n2) {
        const float bv = bu2[n2 * 16 + l16];
        acc2[n2][0] = bv; acc2[n2][1] = bv; acc2[n2][2] = bv; acc2[n2][3] = bv;
    }
#pragma unroll
    for (int kb = 0; kb < 4; ++kb) {
        bf16x8 a = *(const bf16x8*)(const void*)(&sA[((kb * 4 + quad) * 64 + mrow) * 8]);
#pragma unroll
        for (int n2 = 0; n2 < 4; ++n2) {
            bf16x8 b = *(const bf16x8*)(const void*)(Wpb + ((size_t)(n2 * 4 + kb) * 64 + l) * 8);
            acc2[n2] = __builtin_amdgcn_mfma_f32_16x16x32_bf16(a, b, acc2[n2], 0, 0, 0);
        }
    }
#pragma unroll
    for (int n2 = 0; n2 < 4; ++n2) {
        const int col = n2 * 16 + l16;
#pragma unroll
        for (int r = 0; r < 4; ++r) {
            const int gn = n0 + w * 16 + quad * 4 + r;
            if (gn < NN) out[(size_t)gn * DN + col] = acc2[n2][r];
        }
    }
}

extern "C" void kernel_launch(void* const* d_in, const int* in_sizes, int n_in,
                              void* d_out, int out_size, void* d_ws, size_t ws_size,
                              hipStream_t stream) {
    const float* x   = (const float*)d_in[0];
    const int*   ei  = (const int*)d_in[1];
    const float* ef  = (const float*)d_in[2];
    const float* W1  = (const float*)d_in[3];
    const float* b1  = (const float*)d_in[4];
    const float* W2  = (const float*)d_in[5];
    const float* b2  = (const float*)d_in[6];
    const float* U1  = (const float*)d_in[7];
    const float* bu1 = (const float*)d_in[8];
    const float* U2  = (const float*)d_in[9];
    const float* bu2 = (const float*)d_in[10];
    float* out = (float*)d_out;

    unsigned short* XAb = (unsigned short*)d_ws;       // [NN,128] bf16
    float* XB   = (float*)(XAb + (size_t)NN * HH);     // [NN,128] f32
    float* Hagg = XB + (size_t)NN * HH;                // [NN,128]
    float* deg  = Hagg + (size_t)NN * HH;              // [NN]
    float* Wc   = deg + NN;                            // [128,128]
    float* cvec = Wc + (size_t)HH * HH;                // [128]
    unsigned short* Wpa = (unsigned short*)(cvec + HH);// [8*6*64*8] bf16 packed
    unsigned short* Wpb = Wpa + 8 * 6 * 64 * 8;        // [4*4*64*8]
    int*   cnt  = (int*)(Wpb + 4 * 4 * 64 * 8);        // [NN]
    int*   pos  = cnt + NN;                            // [NN]
    int*   boff = pos + NN;                            // [1024]
    int*   es   = boff + 1024;                         // [NE]
    float4* ef4 = (float4*)(es + NE);                  // [NE]
    const size_t need = (size_t)((char*)(ef4 + NE) - (char*)d_ws);

    const int nblk  = (NN + NT - 1) / NT;
    const int nblk2 = (NN + NT2 - 1) / NT2;

    k_fold<<<65, 256, 0, stream>>>(W2, U1, b2, Wc, cvec);
    k_pack<<<16, 256, 0, stream>>>(U1, Wc, U2, Wpa, Wpb);

    if (ws_size >= need) {
        hipMemsetAsync(cnt, 0, (size_t)NN * sizeof(int), stream);
        k_xproj<<<nblk, 256, 0, stream>>>(x, W1, XAb, XB);
        k_hist<<<(NE + 255) / 256, 256, 0, stream>>>(ei, cnt);
        k_scan_a<<<NBLK_SCAN, SCAN_B, 0, stream>>>(cnt, pos, boff);
        k_scan_b<<<1, 512, 0, stream>>>(boff);
        k_scatter<<<(NE + 255) / 256, 256, 0, stream>>>(ei, ef, pos, boff, es, ef4);
        k_agg<<<(NN + 3) / 4, 256, 0, stream>>>(es, ef4, pos, boff, cnt, XAb, XB, W1, b1, Hagg, deg);
    } else {
        hipMemsetAsync(Hagg, 0, ((size_t)NN * HH + NN) * sizeof(float), stream);
        k_xproj<<<nblk, 256, 0, stream>>>(x, W1, XAb, XB);
        k_edge_atomic<<<NE / 4, 256, 0, stream>>>(ei, ef, W1, b1, XAb, XB, Hagg, deg);
    }
    k_update<<<nblk2, 256, 0, stream>>>(x, Hagg, deg, Wpa, Wpb, cvec, bu1, bu2, out);
}

// Round 10
// 352.589 us; speedup vs baseline: 1.1760x; 1.1760x over previous
//
#include <hip/hip_runtime.h>
#include <math.h>

#define NN 100000       // N_NODES
#define NE 800000       // N_EDGES
#define DN 64           // D_NODE
#define DE 4            // D_EDGE
#define HH 128          // H_MSG == H_UPD
#define NT 64           // nodes per block (k_xproj MFMA)
#define NT2 64          // nodes per block (k_update, MFMA)
#define SCAN_B 256
#define NBLK_SCAN ((NN + SCAN_B - 1) / SCAN_B)   // 391

using bf16x8 = __attribute__((ext_vector_type(8))) short;
using f32x4  = __attribute__((ext_vector_type(4))) float;

// bf16 helpers (manual, RNE)
__device__ __forceinline__ unsigned short f2bf(float f) {
    unsigned int u = __float_as_uint(f);
    unsigned int r = (u + 0x7fffu + ((u >> 16) & 1u)) >> 16;
    return (unsigned short)r;
}
__device__ __forceinline__ float bf2f(unsigned short h) {
    return __uint_as_float(((unsigned int)h) << 16);
}
__device__ __forceinline__ float2 bfpair2f(unsigned int v) {
    return make_float2(__uint_as_float(v << 16),
                       __uint_as_float(v & 0xffff0000u));
}

// ---------------------------------------------------------------------------
// Kernel 1 (MFMA): [XA(bf16) | XB(f32)] = x @ [W1[0:64,:] | W1[64:128,:]]
// 64 nodes/block, 4 waves; K=64 (2 kb), N=256 (16 n-tiles).
// A-frag: lane l holds A[m=l&15][k=kb*32+(l>>4)*8+j]; C/D: col=l&15, row=(l>>4)*4+r.
// ---------------------------------------------------------------------------
__global__ __launch_bounds__(256) void k_xproj(const float* __restrict__ x,
                                               const unsigned short* __restrict__ Wpx,
                                               unsigned short* __restrict__ XAb,
                                               float* __restrict__ XB) {
    __shared__ unsigned short sA[8 * 64 * 8];   // 8 KB; [Q=kb*4+quad][m][j]
    const int n0 = blockIdx.x * NT;
    const int t  = threadIdx.x;
    const int w    = t >> 6;
    const int l    = t & 63;
    const int quad = l >> 4;
    const int l16  = l & 15;

    // stage x (64 nodes x 64 k) bf16 into A-frag layout
#pragma unroll
    for (int it = 0; it < 4; ++it) {
        const int flat = t + it * 256;    // node*16 + c
        const int node = flat >> 4;
        const int c    = flat & 15;
        const int gn   = n0 + node;
        float4 v = make_float4(0.f, 0.f, 0.f, 0.f);
        if (gn < NN) v = *(const float4*)(x + (size_t)gn * DN + c * 4);
        const int k = c * 4, Q = k >> 3, j0 = k & 7;
        uint2 pk;
        pk.x = (unsigned)f2bf(v.x) | ((unsigned)f2bf(v.y) << 16);
        pk.y = (unsigned)f2bf(v.z) | ((unsigned)f2bf(v.w) << 16);
        *(uint2*)(&sA[(Q * 64 + node) * 8 + j0]) = pk;
    }
    __syncthreads();

    const int mrow = w * 16 + l16;
    f32x4 acc[16];
#pragma unroll
    for (int nt = 0; nt < 16; ++nt) { acc[nt][0] = 0.f; acc[nt][1] = 0.f; acc[nt][2] = 0.f; acc[nt][3] = 0.f; }

#pragma unroll
    for (int kb = 0; kb < 2; ++kb) {
        bf16x8 a = *(const bf16x8*)(const void*)(&sA[((kb * 4 + quad) * 64 + mrow) * 8]);
#pragma unroll
        for (int nt = 0; nt < 16; ++nt) {
            bf16x8 b = *(const bf16x8*)(const void*)(Wpx + ((size_t)(nt * 2 + kb) * 64 + l) * 8);
            acc[nt] = __builtin_amdgcn_mfma_f32_16x16x32_bf16(a, b, acc[nt], 0, 0, 0);
        }
    }
    // store: tiles 0..7 -> XA (bf16), tiles 8..15 -> XB (f32)
#pragma unroll
    for (int nt = 0; nt < 8; ++nt) {
        const int col = nt * 16 + l16;
#pragma unroll
        for (int r = 0; r < 4; ++r) {
            const int gn = n0 + w * 16 + quad * 4 + r;
            if (gn < NN) XAb[(size_t)gn * HH + col] = f2bf(acc[nt][r]);
        }
    }
#pragma unroll
    for (int nt = 8; nt < 16; ++nt) {
        const int col = (nt - 8) * 16 + l16;
#pragma unroll
        for (int r = 0; r < 4; ++r) {
            const int gn = n0 + w * 16 + quad * 4 + r;
            if (gn < NN) XB[(size_t)gn * HH + col] = acc[nt][r];
        }
    }
}

// ---------------------------------------------------------------------------
// Fold kernel: Wc = W2 @ U1[64:128,:];  cvec = b2 @ U1[64:128,:]
// ---------------------------------------------------------------------------
__global__ __launch_bounds__(256) void k_fold(const float* __restrict__ W2,
                                              const float* __restrict__ U1,
                                              const float* __restrict__ b2,
                                              float* __restrict__ Wc,
                                              float* __restrict__ cvec) {
    const int idx = blockIdx.x * 256 + threadIdx.x;
    const float* u1b = U1 + (size_t)DN * HH;
    if (blockIdx.x < 64) {
        const int r = idx >> 7;
        const int c = idx & 127;
        float acc = 0.f;
#pragma unroll 8
        for (int j = 0; j < DN; ++j)
            acc = fmaf(W2[(size_t)r * DN + j], u1b[(size_t)j * HH + c], acc);
        Wc[(size_t)r * HH + c] = acc;
    } else if (threadIdx.x < HH) {
        const int c = threadIdx.x;
        float acc = 0.f;
#pragma unroll 8
        for (int j = 0; j < DN; ++j)
            acc = fmaf(b2[j], u1b[(size_t)j * HH + c], acc);
        cvec[c] = acc;
    }
}

// ---------------------------------------------------------------------------
// Pack kernel: weights -> bf16 B-fragment layout for mfma_f32_16x16x32_bf16.
// B-frag: lane l holds B[k = kb*32 + (l>>4)*8 + j][n = ntile*16 + (l&15)].
// Wpa: [U1[0:64] ; Wc] (K=192,N=128) -> [n(8)][kb(6)][l][j]
// Wpb: U2 (K=128,N=64)               -> [n(4)][kb(4)][l][j]
// Wpx: [W1[0:64] | W1[64:128]] (K=64, N=256 combined) -> [nt(16)][kb(2)][l][j]
// ---------------------------------------------------------------------------
__global__ __launch_bounds__(256) void k_pack(const float* __restrict__ U1,
                                              const float* __restrict__ Wc,
                                              const float* __restrict__ U2,
                                              const float* __restrict__ W1,
                                              unsigned short* __restrict__ Wpa,
                                              unsigned short* __restrict__ Wpb,
                                              unsigned short* __restrict__ Wpx) {
    const int tid = blockIdx.x * 256 + threadIdx.x;
    if (tid < 3072) {
        const int l  = tid & 63;
        const int kb = (tid >> 6) % 6;
        const int n  = tid / 384;
        const int kbase = kb * 32 + (l >> 4) * 8;
        const int col   = n * 16 + (l & 15);
        unsigned short tmp[8];
#pragma unroll
        for (int j = 0; j < 8; ++j) {
            const int k = kbase + j;
            const float v = (k < DN) ? U1[(size_t)k * HH + col]
                                     : Wc[(size_t)(k - DN) * HH + col];
            tmp[j] = f2bf(v);
        }
        *(uint4*)(Wpa + (size_t)tid * 8) = *(const uint4*)tmp;
    } else if (tid < 4096) {
        const int t2 = tid - 3072;
        const int l  = t2 & 63;
        const int kb = (t2 >> 6) & 3;
        const int n2 = t2 >> 8;
        const int kbase = kb * 32 + (l >> 4) * 8;
        const int col   = n2 * 16 + (l & 15);
        unsigned short tmp[8];
#pragma unroll
        for (int j = 0; j < 8; ++j) tmp[j] = f2bf(U2[(size_t)(kbase + j) * DN + col]);
        *(uint4*)(Wpb + (size_t)t2 * 8) = *(const uint4*)tmp;
    } else if (tid < 6144) {
        const int t3 = tid - 4096;
        const int l  = t3 & 63;
        const int kb = (t3 >> 6) & 1;
        const int nt = t3 >> 7;               // 0..15
        const int kbase = kb * 32 + (l >> 4) * 8;
        const int row0  = (nt < 8) ? 0 : DN;  // XA from rows 0..63, XB from 64..127
        const int col   = ((nt & 7) * 16) + (l & 15);
        unsigned short tmp[8];
#pragma unroll
        for (int j = 0; j < 8; ++j)
            tmp[j] = f2bf(W1[(size_t)(row0 + kbase + j) * HH + col]);
        *(uint4*)(Wpx + (size_t)t3 * 8) = *(const uint4*)tmp;
    }
}

// ---------------------------------------------------------------------------
// Counting sort by destination
// ---------------------------------------------------------------------------
__global__ __launch_bounds__(256) void k_hist(const int* __restrict__ ei,
                                              int* __restrict__ cnt) {
    const int e = blockIdx.x * 256 + threadIdx.x;
    if (e < NE) atomicAdd(&cnt[ei[NE + e]], 1);
}

__global__ __launch_bounds__(SCAN_B) void k_scan_a(const int* __restrict__ cnt,
                                                   int* __restrict__ pos,
                                                   int* __restrict__ bsum) {
    __shared__ int sh[SCAN_B];
    const int n = blockIdx.x * SCAN_B + threadIdx.x;
    const int c = (n < NN) ? cnt[n] : 0;
    sh[threadIdx.x] = c;
    __syncthreads();
    int v = c;
#pragma unroll
    for (int off = 1; off < SCAN_B; off <<= 1) {
        int add = (threadIdx.x >= off) ? sh[threadIdx.x - off] : 0;
        __syncthreads();
        v += add;
        sh[threadIdx.x] = v;
        __syncthreads();
    }
    if (n < NN) pos[n] = v - c;
    if (threadIdx.x == SCAN_B - 1) bsum[blockIdx.x] = v;
}

__global__ __launch_bounds__(512) void k_scan_b(int* __restrict__ bsum) {
    __shared__ int sh[512];
    const int i = threadIdx.x;
    const int c = (i < NBLK_SCAN) ? bsum[i] : 0;
    sh[i] = c;
    __syncthreads();
    int v = c;
#pragma unroll
    for (int off = 1; off < 512; off <<= 1) {
        int add = (i >= off) ? sh[i - off] : 0;
        __syncthreads();
        v += add;
        sh[i] = v;
        __syncthreads();
    }
    if (i < NBLK_SCAN) bsum[i] = v - c;
}

__global__ __launch_bounds__(256) void k_scatter(const int* __restrict__ ei,
                                                 const float* __restrict__ ef,
                                                 int* __restrict__ pos,
                                                 const int* __restrict__ boff,
                                                 int* __restrict__ es,
                                                 float4* __restrict__ ef4) {
    const int e = blockIdx.x * 256 + threadIdx.x;
    if (e >= NE) return;
    const int s = ei[e];
    const int d = ei[NE + e];
    const int slot = atomicAdd(&pos[d], 1) + boff[d >> 8];
    es[slot] = s;
    ef4[slot] = make_float4(log1pf(ef[e * 4 + 0]), log1pf(ef[e * 4 + 1]),
                            log1pf(ef[e * 4 + 2]), log1pf(ef[e * 4 + 3]));
}

// ---------------------------------------------------------------------------
// Segmented reduce, one wave per node (R8 form: depth-1 pipeline, VGPR~20).
// ---------------------------------------------------------------------------
__global__ __launch_bounds__(256) void k_agg(const int* __restrict__ es,
                                             const float4* __restrict__ ef4,
                                             const int* __restrict__ pos,
                                             const int* __restrict__ boff,
                                             const int* __restrict__ cnt,
                                             const unsigned short* __restrict__ XAb,
                                             const float* __restrict__ XB,
                                             const float* __restrict__ W1,
                                             const float* __restrict__ b1,
                                             float* __restrict__ Hagg,
                                             float* __restrict__ deg) {
    const int wave = threadIdx.x >> 6;
    const int lane = threadIdx.x & 63;
    const int d = blockIdx.x * 4 + wave;
    if (d >= NN) return;
    const int c     = cnt[d];
    const int end   = pos[d] + boff[d >> 8];
    const int start = end - c;
    const int j0    = lane * 2;

    const float* we = W1 + 128 * HH;
    const float2 xb = *(const float2*)(XB + (size_t)d * HH + j0);
    const float2 bb = *(const float2*)(b1 + j0);
    const float base0 = xb.x + bb.x;
    const float base1 = xb.y + bb.y;
    const float2 wv0 = *(const float2*)(we + 0 * HH + j0);
    const float2 wv1 = *(const float2*)(we + 1 * HH + j0);
    const float2 wv2 = *(const float2*)(we + 2 * HH + j0);
    const float2 wv3 = *(const float2*)(we + 3 * HH + j0);

    float acc0 = 0.f, acc1 = 0.f;
    if (c > 0) {
        float4 f_cur = ef4[start];
        unsigned int a_cur = *(const unsigned int*)(XAb + (size_t)es[start] * HH + j0);
        for (int k = start; k < end; ++k) {
            const float4 f = f_cur;
            const float2 a = bfpair2f(a_cur);
            if (k + 1 < end) {
                const int sn = es[k + 1];
                f_cur = ef4[k + 1];
                a_cur = *(const unsigned int*)(XAb + (size_t)sn * HH + j0);
            }
            float h0 = a.x + base0;
            float h1 = a.y + base1;
            h0 = fmaf(f.x, wv0.x, h0); h0 = fmaf(f.y, wv1.x, h0);
            h0 = fmaf(f.z, wv2.x, h0); h0 = fmaf(f.w, wv3.x, h0);
            h1 = fmaf(f.x, wv0.y, h1); h1 = fmaf(f.y, wv1.y, h1);
            h1 = fmaf(f.z, wv2.y, h1); h1 = fmaf(f.w, wv3.y, h1);
            acc0 += fmaxf(h0, 0.f);
            acc1 += fmaxf(h1, 0.f);
        }
    }
    *(float2*)(Hagg + (size_t)d * HH + j0) = make_float2(acc0, acc1);
    if (lane == 0) deg[d] = (float)c;
}

// ---------------------------------------------------------------------------
// Fallback edge kernel (atomic path)
// ---------------------------------------------------------------------------
__global__ __launch_bounds__(256) void k_edge_atomic(const int* __restrict__ ei,
                                                     const float* __restrict__ ef,
                                                     const float* __restrict__ W1,
                                                     const float* __restrict__ b1,
                                                     const unsigned short* __restrict__ XAb,
                                                     const float* __restrict__ XB,
                                                     float* __restrict__ Hagg,
                                                     float* __restrict__ deg) {
    const int wave = threadIdx.x >> 6;
    const int lane = threadIdx.x & 63;
    const long e = (long)blockIdx.x * 4 + wave;
    if (e >= NE) return;
    const int s = ei[e];
    const int d = ei[NE + e];

    float t = 0.f;
    if (lane < DE) t = log1pf(ef[e * DE + lane]);
    const float l0 = __shfl(t, 0);
    const float l1 = __shfl(t, 1);
    const float l2 = __shfl(t, 2);
    const float l3 = __shfl(t, 3);

    const float* we = W1 + 128 * HH;
    const size_t sb = (size_t)s * HH;
    const size_t db = (size_t)d * HH;
#pragma unroll
    for (int r = 0; r < 2; ++r) {
        const int j = lane + r * 64;
        float h = bf2f(XAb[sb + j]) + XB[db + j] + b1[j];
        h = fmaf(l0, we[0 * HH + j], h);
        h = fmaf(l1, we[1 * HH + j], h);
        h = fmaf(l2, we[2 * HH + j], h);
        h = fmaf(l3, we[3 * HH + j], h);
        h = fmaxf(h, 0.f);
        atomicAdd(&Hagg[db + j], h);
    }
    if (lane == 0) atomicAdd(&deg[d], 1.f);
}

// ---------------------------------------------------------------------------
// Kernel 3 (MFMA): 64 nodes/block, 4 waves (unchanged from R8).
// ---------------------------------------------------------------------------
__global__ __launch_bounds__(256) void k_update(const float* __restrict__ x,
                                                const float* __restrict__ Hagg,
                                                const float* __restrict__ deg,
                                                const unsigned short* __restrict__ Wpa,
                                                const unsigned short* __restrict__ Wpb,
                                                const float* __restrict__ cvec,
                                                const float* __restrict__ bu1,
                                                const float* __restrict__ bu2,
                                                float* __restrict__ out) {
    __shared__ unsigned short sA[6 * 4 * 64 * 8];   // 24 KB
    __shared__ float sdeg[NT2];
    const int n0 = blockIdx.x * NT2;
    const int t  = threadIdx.x;
    const int w    = t >> 6;
    const int l    = t & 63;
    const int quad = l >> 4;
    const int l16  = l & 15;

#pragma unroll
    for (int it = 0; it < 4; ++it) {
        const int flat = t + it * 256;
        const int node = flat >> 4;
        const int c    = flat & 15;
        const int gn   = n0 + node;
        float4 v = make_float4(0.f, 0.f, 0.f, 0.f);
        if (gn < NN) v = *(const float4*)(x + (size_t)gn * DN + c * 4);
        const int k = c * 4, Q = k >> 3, j0 = k & 7;
        uint2 pk;
        pk.x = (unsigned)f2bf(v.x) | ((unsigned)f2bf(v.y) << 16);
        pk.y = (unsigned)f2bf(v.z) | ((unsigned)f2bf(v.w) << 16);
        *(uint2*)(&sA[(Q * 64 + node) * 8 + j0]) = pk;
    }
#pragma unroll
    for (int it = 0; it < 8; ++it) {
        const int flat = t + it * 256;
        const int node = flat >> 5;
        const int c    = flat & 31;
        const int gn   = n0 + node;
        float4 v = make_float4(0.f, 0.f, 0.f, 0.f);
        if (gn < NN) v = *(const float4*)(Hagg + (size_t)gn * HH + c * 4);
        const int k = DN + c * 4, Q = k >> 3, j0 = k & 7;
        uint2 pk;
        pk.x = (unsigned)f2bf(v.x) | ((unsigned)f2bf(v.y) << 16);
        pk.y = (unsigned)f2bf(v.z) | ((unsigned)f2bf(v.w) << 16);
        *(uint2*)(&sA[(Q * 64 + node) * 8 + j0]) = pk;
    }
    if (t < NT2) sdeg[t] = (n0 + t < NN) ? deg[n0 + t] : 0.f;
    __syncthreads();

    f32x4 acc[8];
#pragma unroll
    for (int n = 0; n < 8; ++n) {
        const int col = n * 16 + l16;
        const float bv = bu1[col];
        const float cv = cvec[col];
#pragma unroll
        for (int r = 0; r < 4; ++r)
            acc[n][r] = fmaf(sdeg[w * 16 + quad * 4 + r], cv, bv);
    }
    const int mrow = w * 16 + l16;
#pragma unroll
    for (int kb = 0; kb < 6; ++kb) {
        bf16x8 a = *(const bf16x8*)(const void*)(&sA[((kb * 4 + quad) * 64 + mrow) * 8]);
#pragma unroll
        for (int n = 0; n < 8; ++n) {
            bf16x8 b = *(const bf16x8*)(const void*)(Wpa + ((size_t)(n * 6 + kb) * 64 + l) * 8);
            acc[n] = __builtin_amdgcn_mfma_f32_16x16x32_bf16(a, b, acc[n], 0, 0, 0);
        }
    }
    __syncthreads();

#pragma unroll
    for (int n = 0; n < 8; ++n) {
        const int col = n * 16 + l16;
        const int Q = col >> 3;
        const int j = col & 7;
#pragma unroll
        for (int r = 0; r < 4; ++r) {
            const int m = w * 16 + quad * 4 + r;
            sA[(Q * 64 + m) * 8 + j] = f2bf(fmaxf(acc[n][r], 0.f));
        }
    }
    __syncthreads();

    f32x4 acc2[4];
#pragma unroll
    for (int n2 = 0; n2 < 4; ++n2) {
        const float bv = bu2[n2 * 16 + l16];
        acc2[n2][0] = bv; acc2[n2][1] = bv; acc2[n2][2] = bv; acc2[n2][3] = bv;
    }
#pragma unroll
    for (int kb = 0; kb < 4; ++kb) {
        bf16x8 a = *(const bf16x8*)(const void*)(&sA[((kb * 4 + quad) * 64 + mrow) * 8]);
#pragma unroll
        for (int n2 = 0; n2 < 4; ++n2) {
            bf16x8 b = *(const bf16x8*)(const void*)(Wpb + ((size_t)(n2 * 4 + kb) * 64 + l) * 8);
            acc2[n2] = __builtin_amdgcn_mfma_f32_16x16x32_bf16(a, b, acc2[n2], 0, 0, 0);
        }
    }
#pragma unroll
    for (int n2 = 0; n2 < 4; ++n2) {
        const int col = n2 * 16 + l16;
#pragma unroll
        for (int r = 0; r < 4; ++r) {
            const int gn = n0 + w * 16 + quad * 4 + r;
            if (gn < NN) out[(size_t)gn * DN + col] = acc2[n2][r];
        }
    }
}

extern "C" void kernel_launch(void* const* d_in, const int* in_sizes, int n_in,
                              void* d_out, int out_size, void* d_ws, size_t ws_size,
                              hipStream_t stream) {
    const float* x   = (const float*)d_in[0];
    const int*   ei  = (const int*)d_in[1];
    const float* ef  = (const float*)d_in[2];
    const float* W1  = (const float*)d_in[3];
    const float* b1  = (const float*)d_in[4];
    const float* W2  = (const float*)d_in[5];
    const float* b2  = (const float*)d_in[6];
    const float* U1  = (const float*)d_in[7];
    const float* bu1 = (const float*)d_in[8];
    const float* U2  = (const float*)d_in[9];
    const float* bu2 = (const float*)d_in[10];
    float* out = (float*)d_out;

    unsigned short* XAb = (unsigned short*)d_ws;       // [NN,128] bf16
    float* XB   = (float*)(XAb + (size_t)NN * HH);     // [NN,128] f32
    float* Hagg = XB + (size_t)NN * HH;                // [NN,128]
    float* deg  = Hagg + (size_t)NN * HH;              // [NN]
    float* Wc   = deg + NN;                            // [128,128]
    float* cvec = Wc + (size_t)HH * HH;                // [128]
    unsigned short* Wpa = (unsigned short*)(cvec + HH);// [8*6*64*8]
    unsigned short* Wpb = Wpa + 8 * 6 * 64 * 8;        // [4*4*64*8]
    unsigned short* Wpx = Wpb + 4 * 4 * 64 * 8;        // [16*2*64*8]
    int*   cnt  = (int*)(Wpx + 16 * 2 * 64 * 8);       // [NN]
    int*   pos  = cnt + NN;                            // [NN]
    int*   boff = pos + NN;                            // [1024]
    int*   es   = boff + 1024;                         // [NE]
    float4* ef4 = (float4*)(es + NE);                  // [NE]
    const size_t need = (size_t)((char*)(ef4 + NE) - (char*)d_ws);

    const int nblk  = (NN + NT - 1) / NT;
    const int nblk2 = (NN + NT2 - 1) / NT2;

    k_fold<<<65, 256, 0, stream>>>(W2, U1, b2, Wc, cvec);
    k_pack<<<24, 256, 0, stream>>>(U1, Wc, U2, W1, Wpa, Wpb, Wpx);

    if (ws_size >= need) {
        hipMemsetAsync(cnt, 0, (size_t)NN * sizeof(int), stream);
        k_xproj<<<nblk, 256, 0, stream>>>(x, Wpx, XAb, XB);
        k_hist<<<(NE + 255) / 256, 256, 0, stream>>>(ei, cnt);
        k_scan_a<<<NBLK_SCAN, SCAN_B, 0, stream>>>(cnt, pos, boff);
        k_scan_b<<<1, 512, 0, stream>>>(boff);
        k_scatter<<<(NE + 255) / 256, 256, 0, stream>>>(ei, ef, pos, boff, es, ef4);
        k_agg<<<(NN + 3) / 4, 256, 0, stream>>>(es, ef4, pos, boff, cnt, XAb, XB, W1, b1, Hagg, deg);
    } else {
        hipMemsetAsync(Hagg, 0, ((size_t)NN * HH + NN) * sizeof(float), stream);
        k_xproj<<<nblk, 256, 0, stream>>>(x, Wpx, XAb, XB);
        k_edge_atomic<<<NE / 4, 256, 0, stream>>>(ei, ef, W1, b1, XAb, XB, Hagg, deg);
    }
    k_update<<<nblk2, 256, 0, stream>>>(x, Hagg, deg, Wpa, Wpb, cvec, bu1, bu2, out);
}